// Round 3
// baseline (324.653 us; speedup 1.0000x reference)
//
#include <hip/hip_runtime.h>

// pred_heatmap: (16,68,224,224) fp32 ; true_landmarks: (16,68,2) fp32
// bell: (128,128) fp32 ; out: scalar fp32 = mean((pred - true_heatmap)^2)
#define N_IMG    1088        // B*L
#define IMG_HW   50176       // 224*224
#define ROW_F4   56          // 224/4
#define SLICES   7           // 1792 f4/slice -> 7 iters/thread exact
#define SLICE_F4 1792
#define N_TOT    54591488.0  // 1088*50176

// d_out is poisoned 0xAA before every timed call -> explicit zero first.
__global__ void zero_out(float* __restrict__ out) { out[0] = 0.0f; }

// One block per (img, slice); branch-free window lookup; per-block
// atomicAdd of the pre-normalized partial into d_out.
__global__ __launch_bounds__(256) void lm_loss_partial(
        const float* __restrict__ pred,
        const float* __restrict__ lms,
        const float* __restrict__ bell,
        float* __restrict__ out) {
    const int img   = blockIdx.x;
    const int slice = blockIdx.y;
    const float4* __restrict__ p4 =
        (const float4*)(pred + (size_t)img * IMG_HW);

    // rintf == jnp.round (half-to-even); landmarks in [0,223] so ints are safe
    const int y_r = (int)rintf(lms[img * 2 + 0]);
    const int x_r = (int)rintf(lms[img * 2 + 1]);
    const int base = slice * SLICE_F4 + (int)threadIdx.x;

    float acc = 0.0f;
    #pragma unroll
    for (int i = 0; i < 7; ++i) {
        const int f = base + i * 256;
        const float4 p = p4[f];

        const int h  = f / ROW_F4;            // magic-mul
        const int w  = (f - h * ROW_F4) * 4;
        const int bx = h - x_r + 64;          // window row (H axis)
        const int by = w - y_r + 64;          // window col (W axis)

        const float* __restrict__ row = bell + (min(max(bx, 0), 127) << 7);
        const bool rowok = ((unsigned)bx < 128u);

        float t0 = row[min(max(by + 0, 0), 127)];
        float t1 = row[min(max(by + 1, 0), 127)];
        float t2 = row[min(max(by + 2, 0), 127)];
        float t3 = row[min(max(by + 3, 0), 127)];
        t0 = (rowok & ((unsigned)(by + 0) < 128u)) ? t0 : 0.0f;
        t1 = (rowok & ((unsigned)(by + 1) < 128u)) ? t1 : 0.0f;
        t2 = (rowok & ((unsigned)(by + 2) < 128u)) ? t2 : 0.0f;
        t3 = (rowok & ((unsigned)(by + 3) < 128u)) ? t3 : 0.0f;

        const float d0 = p.x - t0;
        const float d1 = p.y - t1;
        const float d2 = p.z - t2;
        const float d3 = p.w - t3;
        acc = fmaf(d0, d0, acc);
        acc = fmaf(d1, d1, acc);
        acc = fmaf(d2, d2, acc);
        acc = fmaf(d3, d3, acc);
    }

    // wave-64 shuffle reduction
    #pragma unroll
    for (int off = 32; off > 0; off >>= 1)
        acc += __shfl_down(acc, off, 64);

    __shared__ float wsum[4];
    const int lane = threadIdx.x & 63;
    const int wid  = threadIdx.x >> 6;
    if (lane == 0) wsum[wid] = acc;
    __syncthreads();
    if (threadIdx.x == 0) {
        const float block_sum = wsum[0] + wsum[1] + wsum[2] + wsum[3];
        // device-scope fp32 atomic; 7616 adds of ~1.3e-4 each -> error ~1e-5
        atomicAdd(out, (float)((double)block_sum / N_TOT));
    }
}

extern "C" void kernel_launch(void* const* d_in, const int* in_sizes, int n_in,
                              void* d_out, int out_size, void* d_ws, size_t ws_size,
                              hipStream_t stream) {
    const float* pred = (const float*)d_in[0];
    const float* lms  = (const float*)d_in[1];
    const float* bell = (const float*)d_in[2];
    float* out        = (float*)d_out;
    (void)d_ws; (void)ws_size;

    zero_out<<<1, 1, 0, stream>>>(out);
    dim3 grid(N_IMG, SLICES);
    lm_loss_partial<<<grid, 256, 0, stream>>>(pred, lms, bell, out);
}

// Round 5
// 285.923 us; speedup vs baseline: 1.1355x; 1.1355x over previous
//
#include <hip/hip_runtime.h>

// pred_heatmap: (16,68,224,224) fp32 ; true_landmarks: (16,68,2) fp32
// bell: (128,128) fp32 ; out: scalar fp32 = mean((pred - true_heatmap)^2)
#define N_IMG    1088        // B*L
#define IMG_HW   50176       // 224*224
#define ROW_F4   56          // 224/4
#define SLICES   7           // 1792 f4/slice -> 7 iters/thread exact
#define SLICE_F4 1792
#define N_PART   (N_IMG * SLICES)   // 7616 partials
#define N_TOT    54591488.0  // 1088*50176

// native vector type (HIP float4 is a struct the nontemporal builtin rejects)
typedef float vfloat4 __attribute__((ext_vector_type(4)));

// Phase 1: grid (N_IMG, SLICES). Nontemporal streaming pred loads; bell
// loads behind an exec-masked branch (out-of-window lanes issue nothing).
__global__ __launch_bounds__(256) void lm_loss_partial(
        const float* __restrict__ pred,
        const float* __restrict__ lms,
        const float* __restrict__ bell,
        float* __restrict__ partials) {
    const int img   = blockIdx.x;
    const int slice = blockIdx.y;
    const vfloat4* __restrict__ p4 =
        (const vfloat4*)(pred + (size_t)img * IMG_HW);

    // rintf == jnp.round (half-to-even)
    const int y_r = (int)rintf(lms[img * 2 + 0]);
    const int x_r = (int)rintf(lms[img * 2 + 1]);
    const int base = slice * SLICE_F4 + (int)threadIdx.x;

    float acc = 0.0f;
    #pragma unroll
    for (int i = 0; i < 7; ++i) {
        const int f = base + i * 256;
        const vfloat4 p = __builtin_nontemporal_load(p4 + f);  // streaming read

        const int h  = f / ROW_F4;            // magic-mul
        const int w  = (f - h * ROW_F4) * 4;
        const int bx = h - x_r + 64;          // window row (H axis)
        const int by = w - y_r + 64;          // window col (W axis)

        float t0 = 0.f, t1 = 0.f, t2 = 0.f, t3 = 0.f;
        if ((unsigned)bx < 128u) {            // exec-masked: skip bell loads
            const float* __restrict__ row = bell + (bx << 7);
            if ((unsigned)(by + 0) < 128u) t0 = row[by + 0];
            if ((unsigned)(by + 1) < 128u) t1 = row[by + 1];
            if ((unsigned)(by + 2) < 128u) t2 = row[by + 2];
            if ((unsigned)(by + 3) < 128u) t3 = row[by + 3];
        }
        const float d0 = p.x - t0;
        const float d1 = p.y - t1;
        const float d2 = p.z - t2;
        const float d3 = p.w - t3;
        acc = fmaf(d0, d0, acc);
        acc = fmaf(d1, d1, acc);
        acc = fmaf(d2, d2, acc);
        acc = fmaf(d3, d3, acc);
    }

    // wave-64 shuffle reduction
    #pragma unroll
    for (int off = 32; off > 0; off >>= 1)
        acc += __shfl_down(acc, off, 64);

    __shared__ float wsum[4];
    const int lane = threadIdx.x & 63;
    const int wid  = threadIdx.x >> 6;
    if (lane == 0) wsum[wid] = acc;
    __syncthreads();
    if (threadIdx.x == 0)
        partials[slice * N_IMG + img] = wsum[0] + wsum[1] + wsum[2] + wsum[3];
}

// Phase 2: single block reduces 7616 partials, writes mean
__global__ __launch_bounds__(256) void lm_loss_final(
        const float* __restrict__ partials,
        float* __restrict__ out) {
    double acc = 0.0;
    for (int i = threadIdx.x; i < N_PART; i += 256)
        acc += (double)partials[i];

    #pragma unroll
    for (int off = 32; off > 0; off >>= 1)
        acc += __shfl_down(acc, off, 64);

    __shared__ double wsum[4];
    const int lane = threadIdx.x & 63;
    const int wid  = threadIdx.x >> 6;
    if (lane == 0) wsum[wid] = acc;
    __syncthreads();
    if (threadIdx.x == 0) {
        const double total = wsum[0] + wsum[1] + wsum[2] + wsum[3];
        out[0] = (float)(total / N_TOT);
    }
}

extern "C" void kernel_launch(void* const* d_in, const int* in_sizes, int n_in,
                              void* d_out, int out_size, void* d_ws, size_t ws_size,
                              hipStream_t stream) {
    const float* pred = (const float*)d_in[0];
    const float* lms  = (const float*)d_in[1];
    const float* bell = (const float*)d_in[2];
    float* out        = (float*)d_out;
    float* partials   = (float*)d_ws;   // 7616 floats, fully rewritten each call

    dim3 grid(N_IMG, SLICES);
    lm_loss_partial<<<grid, 256, 0, stream>>>(pred, lms, bell, partials);
    lm_loss_final<<<1, 256, 0, stream>>>(partials, out);
}